// Round 3
// baseline (416.390 us; speedup 1.0000x reference)
//
#include <hip/hip_runtime.h>
#include <hip/hip_fp16.h>
#include <math.h>

#define N_NODES 100000
#define N_EDGES 1600000
#define IN_F 256
#define OUT_F 128
#define SCAN_TPB 256
#define SCAN_EPB 1024

// hist partition: R node ranges x C edge chunks, packed 16-bit LDS bins
#define HR 4
#define HRANGE 25000          // nodes per range (50 KB LDS as packed u16)
#define HC 64
#define HCHUNK 25000          // edges per chunk (divisible by 4)
#define PWORDS (N_NODES / 2)  // packed words per chunk row (50,000)

// gemm tiling
#define GM_ROWS 64            // rows per block (fine granularity: 1563 blocks)

typedef _Float16 h8 __attribute__((ext_vector_type(8)));
typedef float f4 __attribute__((ext_vector_type(4)));

// ---------------- LDS-privatized histogram, packed 16-bit bins ----------------
// grid = HC x (2 type x HR) = 512 blocks. type 0: dst (+ per-edge rank),
// type 1: src. Counts per (chunk,node) < 25000 so 16-bit halves never overflow.
__global__ __launch_bounds__(256) void hist_kernel(
        const int* __restrict__ src, const int* __restrict__ dst,
        int* __restrict__ rank, unsigned int* __restrict__ partial_in,
        unsigned int* __restrict__ partial_out) {
    __shared__ unsigned int bins[HRANGE / 2];   // 50,000 B
    int b = blockIdx.x;
    int c = b >> 3;          // 0..63 chunk
    int tr = b & 7;
    int type = tr >> 2;      // 0 = dst, 1 = src
    int r = tr & 3;          // 0..3 range
    for (int i = threadIdx.x; i < HRANGE / 2; i += 256) bins[i] = 0;
    __syncthreads();
    const int* nodes = type ? src : dst;
    const int e0 = c * HCHUNK;
    const int lo = r * HRANGE;
    const int ngroups = HCHUNK / 4;   // 6250
    for (int g = threadIdx.x; g < ngroups; g += 256) {
        int e = e0 + g * 4;
        int4 n4 = *(const int4*)(nodes + e);
        int nn[4] = {n4.x, n4.y, n4.z, n4.w};
        #pragma unroll
        for (int j = 0; j < 4; ++j) {
            unsigned loc = (unsigned)(nn[j] - lo);
            if (loc < (unsigned)HRANGE) {
                unsigned sh = (loc & 1) * 16;
                unsigned old = atomicAdd(&bins[loc >> 1], 1u << sh);
                if (type == 0) rank[e + j] = (int)((old >> sh) & 0xffffu);
            }
        }
    }
    __syncthreads();
    unsigned int* part = type ? partial_out : partial_in;
    unsigned int* dstp = part + (size_t)c * PWORDS + (lo >> 1);
    for (int i = threadIdx.x; i < HRANGE / 2; i += 256) dstp[i] = bins[i];
}

// ---------------- fused reduce: deg_in + chunk_base16 + rs_out + scan partials ----------------
// block = 256 threads x 4 nodes = 1024 nodes (matches SCAN_EPB)
__global__ __launch_bounds__(256) void fused_reduce_kernel(
        const unsigned int* __restrict__ partial_in,
        const unsigned int* __restrict__ partial_out,
        unsigned short* __restrict__ chunk_base16,
        int* __restrict__ deg_in, float* __restrict__ rs_out,
        int* __restrict__ spart, int N) {
    __shared__ int tmp[256];
    int t = threadIdx.x;
    int n0 = blockIdx.x * SCAN_EPB + t * 4;
    int run[4] = {0, 0, 0, 0};
    int sout[4] = {0, 0, 0, 0};
    if (n0 < N) {
        const int w0 = n0 >> 1;    // word offset (n0 multiple of 4 -> even)
        #pragma unroll 4
        for (int c = 0; c < HC; ++c) {
            // chunk_base = running sum of per-chunk dst counts
            ushort4 cb;
            cb.x = (unsigned short)run[0]; cb.y = (unsigned short)run[1];
            cb.z = (unsigned short)run[2]; cb.w = (unsigned short)run[3];
            *(ushort4*)(chunk_base16 + (size_t)c * N_NODES + n0) = cb;
            uint2 pi = *(const uint2*)(partial_in + (size_t)c * PWORDS + w0);
            run[0] += (int)(pi.x & 0xffffu);  run[1] += (int)(pi.x >> 16);
            run[2] += (int)(pi.y & 0xffffu);  run[3] += (int)(pi.y >> 16);
            uint2 po = *(const uint2*)(partial_out + (size_t)c * PWORDS + w0);
            sout[0] += (int)(po.x & 0xffffu); sout[1] += (int)(po.x >> 16);
            sout[2] += (int)(po.y & 0xffffu); sout[3] += (int)(po.y >> 16);
        }
        *(int4*)(deg_in + n0) = make_int4(run[0], run[1], run[2], run[3]);
        float4 rs;
        rs.x = rsqrtf((float)(sout[0] < 1 ? 1 : sout[0]));
        rs.y = rsqrtf((float)(sout[1] < 1 ? 1 : sout[1]));
        rs.z = rsqrtf((float)(sout[2] < 1 ? 1 : sout[2]));
        rs.w = rsqrtf((float)(sout[3] < 1 ? 1 : sout[3]));
        *(float4*)(rs_out + n0) = rs;
    }
    tmp[t] = run[0] + run[1] + run[2] + run[3];
    __syncthreads();
    for (int off = 128; off > 0; off >>= 1) {
        if (t < off) tmp[t] += tmp[t + off];
        __syncthreads();
    }
    if (t == 0) spart[blockIdx.x] = tmp[0];
}

// ---------------- scan over block partials + final row_ptr ----------------
__global__ __launch_bounds__(128) void scan_part2(const int* __restrict__ partials,
                                                  int* __restrict__ bases, int nb) {
    __shared__ int tmp[128];
    int t = threadIdx.x;
    int v = (t < nb) ? partials[t] : 0;
    tmp[t] = v;
    __syncthreads();
    int x = v;
    for (int off = 1; off < 128; off <<= 1) {
        int y = (t >= off) ? tmp[t - off] : 0;
        __syncthreads();
        x += y;
        tmp[t] = x;
        __syncthreads();
    }
    if (t < nb) bases[t] = x - v;   // exclusive
}

__global__ __launch_bounds__(SCAN_TPB) void scan_part3(const int* __restrict__ deg,
                                                       const int* __restrict__ bases,
                                                       int* __restrict__ row_ptr, int N) {
    __shared__ int tmp[SCAN_TPB];
    int t = threadIdx.x;
    int i0 = blockIdx.x * SCAN_EPB + t * 4;
    int v[4];
    int s = 0;
    #pragma unroll
    for (int j = 0; j < 4; ++j) { v[j] = (i0 + j < N) ? deg[i0 + j] : 0; s += v[j]; }
    tmp[t] = s;
    __syncthreads();
    int x = s;
    for (int off = 1; off < SCAN_TPB; off <<= 1) {
        int y = (t >= off) ? tmp[t - off] : 0;
        __syncthreads();
        x += y;
        tmp[t] = x;
        __syncthreads();
    }
    int excl = bases[blockIdx.x] + x - s;
    #pragma unroll
    for (int j = 0; j < 4; ++j) {
        if (i0 + j < N) row_ptr[i0 + j] = excl;
        excl += v[j];
    }
    if (blockIdx.x == gridDim.x - 1 && t == SCAN_TPB - 1) row_ptr[N] = bases[blockIdx.x] + x;
}

// ---------------- atomic-free fill: dst-grouped packed (src, ew), int4 loads ----------------
__global__ __launch_bounds__(256) void fill_kernel(
        const int* __restrict__ src, const int* __restrict__ dst,
        const float* __restrict__ ew, const int* __restrict__ row_ptr,
        const unsigned short* __restrict__ chunk_base16,
        const int* __restrict__ rank, int2* __restrict__ ed, int E) {
    int e0 = (blockIdx.x * 256 + threadIdx.x) * 4;
    if (e0 >= E) return;
    int4 s4 = *(const int4*)(src + e0);
    int4 d4 = *(const int4*)(dst + e0);
    float4 w4 = *(const float4*)(ew + e0);
    int4 r4 = *(const int4*)(rank + e0);
    int c = e0 / HCHUNK;   // groups never straddle chunks (HCHUNK % 4 == 0)
    const unsigned short* cb = chunk_base16 + (size_t)c * N_NODES;
    int dd[4] = {d4.x, d4.y, d4.z, d4.w};
    int ss[4] = {s4.x, s4.y, s4.z, s4.w};
    int rr[4] = {r4.x, r4.y, r4.z, r4.w};
    float ww[4] = {w4.x, w4.y, w4.z, w4.w};
    #pragma unroll
    for (int j = 0; j < 4; ++j) {
        int d = dd[j];
        int p = row_ptr[d] + (int)cb[d] + rr[j];
        unsigned long long v = (unsigned long long)(unsigned int)ss[j] |
                               ((unsigned long long)(unsigned int)__float_as_int(ww[j]) << 32);
        __builtin_nontemporal_store(v, (unsigned long long*)&ed[p]);
    }
}

// ---------------- Wt[n][k] = (f16) W[k][n] ----------------
__global__ void wt_kernel(const float* __restrict__ W, _Float16* __restrict__ Wt) {
    int i = blockIdx.x * blockDim.x + threadIdx.x;
    if (i < IN_F * OUT_F) {
        int n = i >> 8;
        int k = i & 255;
        Wt[i] = (_Float16)W[k * OUT_F + n];
    }
}

// ---------------- h = tanh(rs[row] * (feat @ W)), f16 MFMA ----------------
// B (Wt, 64 KB f16) staged once per block in XOR-swizzled LDS (conflict-free
// ds_read_b128, verified round 2). A-loads are explicitly software-pipelined
// 1-deep in REGISTERS: all 8 float4 loads + 2 B ds_reads for k-step k+1 are
// issued BEFORE consuming buffer k, so the waitcnt in front of the cvt chain
// is vmcnt(8), keeping ~8 KB/wave in flight across the whole cvt+MFMA block
// (the round-0/1/2 versions all collapsed to ~1 outstanding wave-load/CU ->
// 800 GB/s latency-serialized). Full unroll keeps buf[k&1] indices static
// (rule: runtime-indexed vector arrays go to scratch).
__global__ __launch_bounds__(256, 2) void gemm_mfma_kernel(
        const float* __restrict__ feat, const _Float16* __restrict__ Wt,
        const float* __restrict__ rs_out, __half* __restrict__ h, int N) {
    __shared__ _Float16 wlds[OUT_F * IN_F];   // 65,536 B
    const int tid = threadIdx.x;

    // stage Wt -> LDS, swizzled: granule gi = row*32 + gc  (16B granules)
    for (int gi = tid; gi < OUT_F * IN_F / 8; gi += 256) {
        int row = gi >> 5;
        int gc  = gi & 31;
        int gs  = gc ^ (row & 7);
        *(int4*)&wlds[(size_t)(row * 32 + gs) * 8] = *(const int4*)&Wt[(size_t)gi * 8];
    }
    __syncthreads();

    const int wave = tid >> 6;
    const int lane = tid & 63;
    const int m = lane & 15;
    const int quad = lane >> 4;
    const int n0 = wave * 32;
    const int brow0 = n0 + m;
    const int brow1 = n0 + 16 + m;
    const int r0 = blockIdx.x * GM_ROWS;

    const float* ap0;
    const float* ap1;
    const float* ap2;
    const float* ap3;
    {
        int a0 = r0 + m;       if (a0 >= N) a0 = 0;
        int a1 = r0 + 16 + m;  if (a1 >= N) a1 = 0;
        int a2 = r0 + 32 + m;  if (a2 >= N) a2 = 0;
        int a3 = r0 + 48 + m;  if (a3 >= N) a3 = 0;
        ap0 = feat + (size_t)a0 * IN_F + quad * 8;
        ap1 = feat + (size_t)a1 * IN_F + quad * 8;
        ap2 = feat + (size_t)a2 * IN_F + quad * 8;
        ap3 = feat + (size_t)a3 * IN_F + quad * 8;
    }

    f4 acc[4][2];
    #pragma unroll
    for (int t = 0; t < 4; ++t) {
        acc[t][0] = (f4){0.f, 0.f, 0.f, 0.f};
        acc[t][1] = (f4){0.f, 0.f, 0.f, 0.f};
    }

    float4 buf[2][8];
    h8 bb[2][2];

    // prologue: prefetch k = 0
    buf[0][0] = *(const float4*)(ap0);     buf[0][1] = *(const float4*)(ap0 + 4);
    buf[0][2] = *(const float4*)(ap1);     buf[0][3] = *(const float4*)(ap1 + 4);
    buf[0][4] = *(const float4*)(ap2);     buf[0][5] = *(const float4*)(ap2 + 4);
    buf[0][6] = *(const float4*)(ap3);     buf[0][7] = *(const float4*)(ap3 + 4);
    {
        const int gc0 = quad ^ (brow0 & 7);
        const int gc1 = quad ^ (brow1 & 7);
        bb[0][0] = *(const h8*)&wlds[(size_t)(brow0 * 32 + gc0) * 8];
        bb[0][1] = *(const h8*)&wlds[(size_t)(brow1 * 32 + gc1) * 8];
    }

    #pragma unroll
    for (int k = 0; k < 8; ++k) {
        const int cur = k & 1;
        const int nxt = cur ^ 1;
        if (k < 7) {   // issue k+1 loads BEFORE consuming k
            const int o = (k + 1) * 32;
            buf[nxt][0] = *(const float4*)(ap0 + o);  buf[nxt][1] = *(const float4*)(ap0 + o + 4);
            buf[nxt][2] = *(const float4*)(ap1 + o);  buf[nxt][3] = *(const float4*)(ap1 + o + 4);
            buf[nxt][4] = *(const float4*)(ap2 + o);  buf[nxt][5] = *(const float4*)(ap2 + o + 4);
            buf[nxt][6] = *(const float4*)(ap3 + o);  buf[nxt][7] = *(const float4*)(ap3 + o + 4);
            const int gc0 = ((k + 1) * 4 + quad) ^ (brow0 & 7);
            const int gc1 = ((k + 1) * 4 + quad) ^ (brow1 & 7);
            bb[nxt][0] = *(const h8*)&wlds[(size_t)(brow0 * 32 + gc0) * 8];
            bb[nxt][1] = *(const h8*)&wlds[(size_t)(brow1 * 32 + gc1) * 8];
        }
        #pragma unroll
        for (int t = 0; t < 4; ++t) {
            float4 lo = buf[cur][t * 2];
            float4 hi = buf[cur][t * 2 + 1];
            h8 a;
            a[0] = (_Float16)lo.x; a[1] = (_Float16)lo.y;
            a[2] = (_Float16)lo.z; a[3] = (_Float16)lo.w;
            a[4] = (_Float16)hi.x; a[5] = (_Float16)hi.y;
            a[6] = (_Float16)hi.z; a[7] = (_Float16)hi.w;
            acc[t][0] = __builtin_amdgcn_mfma_f32_16x16x32_f16(a, bb[cur][0], acc[t][0], 0, 0, 0);
            acc[t][1] = __builtin_amdgcn_mfma_f32_16x16x32_f16(a, bb[cur][1], acc[t][1], 0, 0, 0);
        }
    }

    #pragma unroll
    for (int t = 0; t < 4; ++t) {
        const int crow = r0 + t * 16 + quad * 4;
        #pragma unroll
        for (int r = 0; r < 4; ++r) {
            const int rr = crow + r;
            if (rr < N) {
                const float rs = rs_out[rr];
                h[(size_t)rr * OUT_F + n0 + m]      = __float2half(tanhf(acc[t][0][r] * rs));
                h[(size_t)rr * OUT_F + n0 + 16 + m] = __float2half(tanhf(acc[t][1][r] * rs));
            }
        }
    }
}

// ---------------- gather: one wave per dst node, 4 edge-slots x 4-deep unroll ----------------
__global__ __launch_bounds__(256) void gather_kernel(
        const __half* __restrict__ h, const int2* __restrict__ ed,
        const int* __restrict__ row_ptr, float* __restrict__ out, int N) {
    int wave = threadIdx.x >> 6;
    int lane = threadIdx.x & 63;
    int node = blockIdx.x * 4 + wave;
    if (node >= N) return;
    int lo = row_ptr[node];
    int hi = row_ptr[node + 1];
    int p = lane >> 4;       // edge slot 0..3
    int c = lane & 15;       // feature octet: feats 8c..8c+7
    float acc[4][8];
    #pragma unroll
    for (int g = 0; g < 4; ++g)
        #pragma unroll
        for (int i = 0; i < 8; ++i) acc[g][i] = 0.f;

    for (int j = lo; j < hi; j += 16) {
        #pragma unroll
        for (int g = 0; g < 4; ++g) {
            int jj = j + g * 4 + p;
            int2 e = (jj < hi) ? ed[jj] : make_int2(0, 0);
            float w = __int_as_float(e.y);
            int4 rrow = *(const int4*)(h + (size_t)e.x * OUT_F + c * 8);
            float2 t;
            t = __half22float2(*(__half2*)&rrow.x); acc[g][0] += w * t.x; acc[g][1] += w * t.y;
            t = __half22float2(*(__half2*)&rrow.y); acc[g][2] += w * t.x; acc[g][3] += w * t.y;
            t = __half22float2(*(__half2*)&rrow.z); acc[g][4] += w * t.x; acc[g][5] += w * t.y;
            t = __half22float2(*(__half2*)&rrow.w); acc[g][6] += w * t.x; acc[g][7] += w * t.y;
        }
    }
    float v[8];
    #pragma unroll
    for (int i = 0; i < 8; ++i) {
        v[i] = (acc[0][i] + acc[1][i]) + (acc[2][i] + acc[3][i]);
        v[i] += __shfl_xor(v[i], 16);
        v[i] += __shfl_xor(v[i], 32);
    }
    if (p == 0) {
        int deg = hi - lo; if (deg < 1) deg = 1;
        float rs = rsqrtf((float)deg);
        float* op = out + (size_t)node * OUT_F + c * 8;
        *(float4*)op       = make_float4(v[0] * rs, v[1] * rs, v[2] * rs, v[3] * rs);
        *(float4*)(op + 4) = make_float4(v[4] * rs, v[5] * rs, v[6] * rs, v[7] * rs);
    }
}

extern "C" void kernel_launch(void* const* d_in, const int* in_sizes, int n_in,
                              void* d_out, int out_size, void* d_ws, size_t ws_size,
                              hipStream_t stream) {
    const float* feat   = (const float*)d_in[0];
    const float* weight = (const float*)d_in[1];
    const float* ew     = (const float*)d_in[2];
    const int*   src    = (const int*)d_in[3];
    const int*   dst    = (const int*)d_in[4];
    float* out = (float*)d_out;

    // workspace layout with aliasing (total 46.07 MB):
    //   ed (12.8M)  overlays partial_in  (dead after fused_reduce)
    //   h  (25.6M)  overlays chunk_base16 + partial_out (dead after fill/reduce)
    char* ws = (char*)d_ws;
    float* rs_out      = (float*)(ws);                       // 400,000
    int*   deg_in      = (int*)(ws + 400000);                // 400,000
    int*   row_ptr     = (int*)(ws + 800000);                // 400,016
    int*   spart       = (int*)(ws + 1200016);               // 512
    int*   sbases      = (int*)(ws + 1200528);               // 512
    int*   rank        = (int*)(ws + 1201056);               // 6,400,000
    unsigned int* partial_in  = (unsigned int*)(ws + 7601056);   // 12,800,000
    int2*  ed          = (int2*)(ws + 7601056);                  // alias ^
    unsigned short* chunk_base16 = (unsigned short*)(ws + 20401056); // 12,800,000
    unsigned int* partial_out = (unsigned int*)(ws + 33201056);  // 12,800,000
    __half* h          = (__half*)(ws + 20401056);               // alias of cb16+p_out
    _Float16* Wt       = (_Float16*)(ws + 46001056);             // 65,536

    const int nb = (N_NODES + SCAN_EPB - 1) / SCAN_EPB;   // 98

    hist_kernel<<<2 * HR * HC, 256, 0, stream>>>(src, dst, rank, partial_in, partial_out);
    fused_reduce_kernel<<<nb, 256, 0, stream>>>(partial_in, partial_out, chunk_base16,
                                                deg_in, rs_out, spart, N_NODES);
    scan_part2<<<1, 128, 0, stream>>>(spart, sbases, nb);
    scan_part3<<<nb, SCAN_TPB, 0, stream>>>(deg_in, sbases, row_ptr, N_NODES);
    fill_kernel<<<(N_EDGES / 4 + 255) / 256, 256, 0, stream>>>(src, dst, ew, row_ptr,
                                                               chunk_base16, rank, ed, N_EDGES);
    wt_kernel<<<(IN_F * OUT_F + 255) / 256, 256, 0, stream>>>(weight, Wt);
    gemm_mfma_kernel<<<(N_NODES + GM_ROWS - 1) / GM_ROWS, 256, 0, stream>>>(feat, Wt, rs_out, h, N_NODES);
    gather_kernel<<<(N_NODES + 3) / 4, 256, 0, stream>>>(h, ed, row_ptr, out, N_NODES);
}

// Round 4
// 377.226 us; speedup vs baseline: 1.1038x; 1.1038x over previous
//
#include <hip/hip_runtime.h>
#include <hip/hip_fp16.h>
#include <math.h>

#define N_NODES 100000
#define N_EDGES 1600000
#define IN_F 256
#define OUT_F 128
#define SCAN_TPB 256
#define SCAN_EPB 1024

// hist partition: R node ranges x C edge chunks, packed 16-bit LDS bins
#define HR 4
#define HRANGE 25000          // nodes per range (50 KB LDS as packed u16)
#define HC 64
#define HCHUNK 25000          // edges per chunk (divisible by 4)
#define PWORDS (N_NODES / 2)  // packed words per chunk row (50,000)

// gemm tiling
#define GM_ROWS 64            // rows per block
#define BK 32                 // K-tile (one 16x16x32 MFMA k-step)

typedef _Float16 h8 __attribute__((ext_vector_type(8)));
typedef float f4 __attribute__((ext_vector_type(4)));

// async global->LDS, 16B per lane; dest is wave-uniform base + lane*16 (linear)
#define GLD16(gp, lp) __builtin_amdgcn_global_load_lds( \
    (const __attribute__((address_space(1))) unsigned int*)(gp), \
    (__attribute__((address_space(3))) unsigned int*)(lp), 16, 0, 0)

// ---------------- LDS-privatized histogram, packed 16-bit bins ----------------
// grid = HC x (2 type x HR) = 512 blocks. type 0: dst (+ per-edge rank),
// type 1: src. Counts per (chunk,node) < 25000 so 16-bit halves never overflow.
__global__ __launch_bounds__(256) void hist_kernel(
        const int* __restrict__ src, const int* __restrict__ dst,
        int* __restrict__ rank, unsigned int* __restrict__ partial_in,
        unsigned int* __restrict__ partial_out) {
    __shared__ unsigned int bins[HRANGE / 2];   // 50,000 B
    int b = blockIdx.x;
    int c = b >> 3;          // 0..63 chunk
    int tr = b & 7;
    int type = tr >> 2;      // 0 = dst, 1 = src
    int r = tr & 3;          // 0..3 range
    for (int i = threadIdx.x; i < HRANGE / 2; i += 256) bins[i] = 0;
    __syncthreads();
    const int* nodes = type ? src : dst;
    const int e0 = c * HCHUNK;
    const int lo = r * HRANGE;
    const int ngroups = HCHUNK / 4;   // 6250
    for (int g = threadIdx.x; g < ngroups; g += 256) {
        int e = e0 + g * 4;
        int4 n4 = *(const int4*)(nodes + e);
        int nn[4] = {n4.x, n4.y, n4.z, n4.w};
        #pragma unroll
        for (int j = 0; j < 4; ++j) {
            unsigned loc = (unsigned)(nn[j] - lo);
            if (loc < (unsigned)HRANGE) {
                unsigned sh = (loc & 1) * 16;
                unsigned old = atomicAdd(&bins[loc >> 1], 1u << sh);
                if (type == 0) rank[e + j] = (int)((old >> sh) & 0xffffu);
            }
        }
    }
    __syncthreads();
    unsigned int* part = type ? partial_out : partial_in;
    unsigned int* dstp = part + (size_t)c * PWORDS + (lo >> 1);
    for (int i = threadIdx.x; i < HRANGE / 2; i += 256) dstp[i] = bins[i];
}

// ---------------- fused reduce: deg_in + chunk_base16 + rs_out + scan partials ----------------
// block = 256 threads x 4 nodes = 1024 nodes (matches SCAN_EPB)
__global__ __launch_bounds__(256) void fused_reduce_kernel(
        const unsigned int* __restrict__ partial_in,
        const unsigned int* __restrict__ partial_out,
        unsigned short* __restrict__ chunk_base16,
        int* __restrict__ deg_in, float* __restrict__ rs_out,
        int* __restrict__ spart, int N) {
    __shared__ int tmp[256];
    int t = threadIdx.x;
    int n0 = blockIdx.x * SCAN_EPB + t * 4;
    int run[4] = {0, 0, 0, 0};
    int sout[4] = {0, 0, 0, 0};
    if (n0 < N) {
        const int w0 = n0 >> 1;    // word offset (n0 multiple of 4 -> even)
        #pragma unroll 4
        for (int c = 0; c < HC; ++c) {
            // chunk_base = running sum of per-chunk dst counts
            ushort4 cb;
            cb.x = (unsigned short)run[0]; cb.y = (unsigned short)run[1];
            cb.z = (unsigned short)run[2]; cb.w = (unsigned short)run[3];
            *(ushort4*)(chunk_base16 + (size_t)c * N_NODES + n0) = cb;
            uint2 pi = *(const uint2*)(partial_in + (size_t)c * PWORDS + w0);
            run[0] += (int)(pi.x & 0xffffu);  run[1] += (int)(pi.x >> 16);
            run[2] += (int)(pi.y & 0xffffu);  run[3] += (int)(pi.y >> 16);
            uint2 po = *(const uint2*)(partial_out + (size_t)c * PWORDS + w0);
            sout[0] += (int)(po.x & 0xffffu); sout[1] += (int)(po.x >> 16);
            sout[2] += (int)(po.y & 0xffffu); sout[3] += (int)(po.y >> 16);
        }
        *(int4*)(deg_in + n0) = make_int4(run[0], run[1], run[2], run[3]);
        float4 rs;
        rs.x = rsqrtf((float)(sout[0] < 1 ? 1 : sout[0]));
        rs.y = rsqrtf((float)(sout[1] < 1 ? 1 : sout[1]));
        rs.z = rsqrtf((float)(sout[2] < 1 ? 1 : sout[2]));
        rs.w = rsqrtf((float)(sout[3] < 1 ? 1 : sout[3]));
        *(float4*)(rs_out + n0) = rs;
    }
    tmp[t] = run[0] + run[1] + run[2] + run[3];
    __syncthreads();
    for (int off = 128; off > 0; off >>= 1) {
        if (t < off) tmp[t] += tmp[t + off];
        __syncthreads();
    }
    if (t == 0) spart[blockIdx.x] = tmp[0];
}

// ---------------- scan over block partials + final row_ptr ----------------
__global__ __launch_bounds__(128) void scan_part2(const int* __restrict__ partials,
                                                  int* __restrict__ bases, int nb) {
    __shared__ int tmp[128];
    int t = threadIdx.x;
    int v = (t < nb) ? partials[t] : 0;
    tmp[t] = v;
    __syncthreads();
    int x = v;
    for (int off = 1; off < 128; off <<= 1) {
        int y = (t >= off) ? tmp[t - off] : 0;
        __syncthreads();
        x += y;
        tmp[t] = x;
        __syncthreads();
    }
    if (t < nb) bases[t] = x - v;   // exclusive
}

__global__ __launch_bounds__(SCAN_TPB) void scan_part3(const int* __restrict__ deg,
                                                       const int* __restrict__ bases,
                                                       int* __restrict__ row_ptr, int N) {
    __shared__ int tmp[SCAN_TPB];
    int t = threadIdx.x;
    int i0 = blockIdx.x * SCAN_EPB + t * 4;
    int v[4];
    int s = 0;
    #pragma unroll
    for (int j = 0; j < 4; ++j) { v[j] = (i0 + j < N) ? deg[i0 + j] : 0; s += v[j]; }
    tmp[t] = s;
    __syncthreads();
    int x = s;
    for (int off = 1; off < SCAN_TPB; off <<= 1) {
        int y = (t >= off) ? tmp[t - off] : 0;
        __syncthreads();
        x += y;
        tmp[t] = x;
        __syncthreads();
    }
    int excl = bases[blockIdx.x] + x - s;
    #pragma unroll
    for (int j = 0; j < 4; ++j) {
        if (i0 + j < N) row_ptr[i0 + j] = excl;
        excl += v[j];
    }
    if (blockIdx.x == gridDim.x - 1 && t == SCAN_TPB - 1) row_ptr[N] = bases[blockIdx.x] + x;
}

// ---------------- atomic-free fill: dst-grouped packed (src, ew), int4 loads ----------------
__global__ __launch_bounds__(256) void fill_kernel(
        const int* __restrict__ src, const int* __restrict__ dst,
        const float* __restrict__ ew, const int* __restrict__ row_ptr,
        const unsigned short* __restrict__ chunk_base16,
        const int* __restrict__ rank, int2* __restrict__ ed, int E) {
    int e0 = (blockIdx.x * 256 + threadIdx.x) * 4;
    if (e0 >= E) return;
    int4 s4 = *(const int4*)(src + e0);
    int4 d4 = *(const int4*)(dst + e0);
    float4 w4 = *(const float4*)(ew + e0);
    int4 r4 = *(const int4*)(rank + e0);
    int c = e0 / HCHUNK;   // groups never straddle chunks (HCHUNK % 4 == 0)
    const unsigned short* cb = chunk_base16 + (size_t)c * N_NODES;
    int dd[4] = {d4.x, d4.y, d4.z, d4.w};
    int ss[4] = {s4.x, s4.y, s4.z, s4.w};
    int rr[4] = {r4.x, r4.y, r4.z, r4.w};
    float ww[4] = {w4.x, w4.y, w4.z, w4.w};
    #pragma unroll
    for (int j = 0; j < 4; ++j) {
        int d = dd[j];
        int p = row_ptr[d] + (int)cb[d] + rr[j];
        unsigned long long v = (unsigned long long)(unsigned int)ss[j] |
                               ((unsigned long long)(unsigned int)__float_as_int(ww[j]) << 32);
        __builtin_nontemporal_store(v, (unsigned long long*)&ed[p]);
    }
}

// ---------------- Wt[n][k] = (f16) W[k][n] ----------------
__global__ void wt_kernel(const float* __restrict__ W, _Float16* __restrict__ Wt) {
    int i = blockIdx.x * blockDim.x + threadIdx.x;
    if (i < IN_F * OUT_F) {
        int n = i >> 8;
        int k = i & 255;
        Wt[i] = (_Float16)W[k * OUT_F + n];
    }
}

__device__ __forceinline__ float fast_tanh(float x) {
    // tanh(x) = 1 - 2/(e^2x + 1); exact at +/-inf, error << f16 quantization
    float e = __expf(2.0f * x);
    return 1.0f - 2.0f / (e + 1.0f);
}

// ---------------- h = tanh(rs[row] * (feat @ W)), f16 MFMA ----------------
// 2-phase async pipeline (T3 minimum recipe): per K-tile (BK=32) both A
// (64x32 f32, 8 KB) and B (128x32 f16, 8 KB) are staged into double-buffered
// LDS via global_load_lds width=16 (4 calls/wave), issued BEFORE computing
// the current tile; one __syncthreads() (vmcnt+lgkm drain) per tile. The
// intrinsic has no dest VGPR, so the compiler cannot sink the loads back to
// the use point (which defeated rounds 0-3; VGPR_Count 88 was the tell).
// A's LDS rows (128 B stride) would be 32-way bank-conflicted, so the 16B
// granule index is XOR-swizzled with (row&7) on the GLOBAL SOURCE address
// (gload_lds writes linearly) and the same XOR is applied on read-back.
// B's 64 B row stride is naturally bank-balanced. LDS total 32 KB -> 4
// blocks/CU (16 waves/CU). rs commutes through the matmul and is applied
// on the f32 accumulator in the epilogue.
__global__ __launch_bounds__(256, 4) void gemm_mfma_kernel(
        const float* __restrict__ feat, const _Float16* __restrict__ Wt,
        const float* __restrict__ rs_out, __half* __restrict__ h, int N) {
    __shared__ float    a_lds[2][GM_ROWS * BK];   // 2 x 8,192 B
    __shared__ _Float16 b_lds[2][OUT_F * BK];     // 2 x 8,192 B

    const int tid  = threadIdx.x;
    const int wave = tid >> 6;
    const int lane = tid & 63;
    const int m    = lane & 15;
    const int quad = lane >> 4;
    const int n0   = wave * 32;
    const int r0   = blockIdx.x * GM_ROWS;

    // ---- staging address setup (wave w: A-calls {2w,2w+1}, B-calls {2w,2w+1})
    // A call i covers LDS rows 8i..8i+7; lane l -> row 8i+(l>>3), LDS granule
    // l&7 (linear), source granule (l&7)^((l>>3)&7)  [row&7 == (l>>3)&7]
    const int l3 = lane >> 3;
    const int ag = (lane & 7) ^ l3;
    int arow0 = r0 + 16 * wave + l3;      if (arow0 >= N) arow0 = N - 1;
    int arow1 = r0 + 16 * wave + 8 + l3;  if (arow1 >= N) arow1 = N - 1;
    const float* ga0 = feat + (size_t)arow0 * IN_F + ag * 4;
    const float* ga1 = feat + (size_t)arow1 * IN_F + ag * 4;
    // B call i covers LDS rows 16i..16i+15; lane l -> row 16i+(l>>2), granule l&3
    const int brow0 = 32 * wave + (lane >> 2);
    const int brow1 = 32 * wave + 16 + (lane >> 2);
    const _Float16* gb0 = Wt + (size_t)brow0 * IN_F + (lane & 3) * 8;
    const _Float16* gb1 = Wt + (size_t)brow1 * IN_F + (lane & 3) * 8;

    f4 acc[4][2];
    #pragma unroll
    for (int t = 0; t < 4; ++t) {
        acc[t][0] = (f4){0.f, 0.f, 0.f, 0.f};
        acc[t][1] = (f4){0.f, 0.f, 0.f, 0.f};
    }

    // prologue: stage k-tile 0 into buf 0
    GLD16(ga0, &a_lds[0][(16 * wave) * BK]);
    GLD16(ga1, &a_lds[0][(16 * wave + 8) * BK]);
    GLD16(gb0, &b_lds[0][(32 * wave) * BK]);
    GLD16(gb1, &b_lds[0][(32 * wave + 16) * BK]);
    __syncthreads();

    #pragma unroll
    for (int kt = 0; kt < IN_F / BK; ++kt) {      // 8 k-tiles
        const int cb = kt & 1;
        if (kt < IN_F / BK - 1) {                 // stage next tile (async)
            const int nb2 = cb ^ 1;
            const int ko = (kt + 1) * BK;
            GLD16(ga0 + ko, &a_lds[nb2][(16 * wave) * BK]);
            GLD16(ga1 + ko, &a_lds[nb2][(16 * wave + 8) * BK]);
            GLD16(gb0 + ko, &b_lds[nb2][(32 * wave) * BK]);
            GLD16(gb1 + ko, &b_lds[nb2][(32 * wave + 16) * BK]);
            __builtin_amdgcn_sched_barrier(0);    // keep stages issued first
        }
        // B fragments: this wave's two 16-col tiles
        h8 b0 = *(const h8*)&b_lds[cb][(n0 + m) * BK + quad * 8];
        h8 b1 = *(const h8*)&b_lds[cb][(n0 + 16 + m) * BK + quad * 8];
        #pragma unroll
        for (int t = 0; t < 4; ++t) {
            const int ar = t * 16 + m;            // row in buffer; ar&7 == m&7
            float4 alo = *(const float4*)&a_lds[cb][ar * BK + (((quad * 2)     ^ (m & 7)) * 4)];
            float4 ahi = *(const float4*)&a_lds[cb][ar * BK + (((quad * 2 + 1) ^ (m & 7)) * 4)];
            h8 a;
            a[0] = (_Float16)alo.x; a[1] = (_Float16)alo.y;
            a[2] = (_Float16)alo.z; a[3] = (_Float16)alo.w;
            a[4] = (_Float16)ahi.x; a[5] = (_Float16)ahi.y;
            a[6] = (_Float16)ahi.z; a[7] = (_Float16)ahi.w;
            acc[t][0] = __builtin_amdgcn_mfma_f32_16x16x32_f16(a, b0, acc[t][0], 0, 0, 0);
            acc[t][1] = __builtin_amdgcn_mfma_f32_16x16x32_f16(a, b1, acc[t][1], 0, 0, 0);
        }
        __syncthreads();   // drains vmcnt(0): staged tile ready; all waves done with cb
    }

    #pragma unroll
    for (int t = 0; t < 4; ++t) {
        const int crow = r0 + t * 16 + quad * 4;
        float4 rs4 = *(const float4*)&rs_out[crow];   // rows contiguous, 16B-aligned
        const float rsv[4] = {rs4.x, rs4.y, rs4.z, rs4.w};
        #pragma unroll
        for (int r = 0; r < 4; ++r) {
            const int rr = crow + r;
            if (rr < N) {
                h[(size_t)rr * OUT_F + n0 + m]      = __float2half(fast_tanh(acc[t][0][r] * rsv[r]));
                h[(size_t)rr * OUT_F + n0 + 16 + m] = __float2half(fast_tanh(acc[t][1][r] * rsv[r]));
            }
        }
    }
}

// ---------------- gather: one wave per dst node, 4 edge-slots x 4-deep unroll ----------------
__global__ __launch_bounds__(256) void gather_kernel(
        const __half* __restrict__ h, const int2* __restrict__ ed,
        const int* __restrict__ row_ptr, float* __restrict__ out, int N) {
    int wave = threadIdx.x >> 6;
    int lane = threadIdx.x & 63;
    int node = blockIdx.x * 4 + wave;
    if (node >= N) return;
    int lo = row_ptr[node];
    int hi = row_ptr[node + 1];
    int p = lane >> 4;       // edge slot 0..3
    int c = lane & 15;       // feature octet: feats 8c..8c+7
    float acc[4][8];
    #pragma unroll
    for (int g = 0; g < 4; ++g)
        #pragma unroll
        for (int i = 0; i < 8; ++i) acc[g][i] = 0.f;

    for (int j = lo; j < hi; j += 16) {
        #pragma unroll
        for (int g = 0; g < 4; ++g) {
            int jj = j + g * 4 + p;
            int2 e = (jj < hi) ? ed[jj] : make_int2(0, 0);
            float w = __int_as_float(e.y);
            int4 rrow = *(const int4*)(h + (size_t)e.x * OUT_F + c * 8);
            float2 t;
            t = __half22float2(*(__half2*)&rrow.x); acc[g][0] += w * t.x; acc[g][1] += w * t.y;
            t = __half22float2(*(__half2*)&rrow.y); acc[g][2] += w * t.x; acc[g][3] += w * t.y;
            t = __half22float2(*(__half2*)&rrow.z); acc[g][4] += w * t.x; acc[g][5] += w * t.y;
            t = __half22float2(*(__half2*)&rrow.w); acc[g][6] += w * t.x; acc[g][7] += w * t.y;
        }
    }
    float v[8];
    #pragma unroll
    for (int i = 0; i < 8; ++i) {
        v[i] = (acc[0][i] + acc[1][i]) + (acc[2][i] + acc[3][i]);
        v[i] += __shfl_xor(v[i], 16);
        v[i] += __shfl_xor(v[i], 32);
    }
    if (p == 0) {
        int deg = hi - lo; if (deg < 1) deg = 1;
        float rs = rsqrtf((float)deg);
        float* op = out + (size_t)node * OUT_F + c * 8;
        *(float4*)op       = make_float4(v[0] * rs, v[1] * rs, v[2] * rs, v[3] * rs);
        *(float4*)(op + 4) = make_float4(v[4] * rs, v[5] * rs, v[6] * rs, v[7] * rs);
    }
}

extern "C" void kernel_launch(void* const* d_in, const int* in_sizes, int n_in,
                              void* d_out, int out_size, void* d_ws, size_t ws_size,
                              hipStream_t stream) {
    const float* feat   = (const float*)d_in[0];
    const float* weight = (const float*)d_in[1];
    const float* ew     = (const float*)d_in[2];
    const int*   src    = (const int*)d_in[3];
    const int*   dst    = (const int*)d_in[4];
    float* out = (float*)d_out;

    // workspace layout with aliasing (total 46.07 MB):
    //   ed (12.8M)  overlays partial_in  (dead after fused_reduce)
    //   h  (25.6M)  overlays chunk_base16 + partial_out (dead after fill/reduce)
    char* ws = (char*)d_ws;
    float* rs_out      = (float*)(ws);                       // 400,000
    int*   deg_in      = (int*)(ws + 400000);                // 400,000
    int*   row_ptr     = (int*)(ws + 800000);                // 400,016
    int*   spart       = (int*)(ws + 1200016);               // 512
    int*   sbases      = (int*)(ws + 1200528);               // 512
    int*   rank        = (int*)(ws + 1201056);               // 6,400,000
    unsigned int* partial_in  = (unsigned int*)(ws + 7601056);   // 12,800,000
    int2*  ed          = (int2*)(ws + 7601056);                  // alias ^
    unsigned short* chunk_base16 = (unsigned short*)(ws + 20401056); // 12,800,000
    unsigned int* partial_out = (unsigned int*)(ws + 33201056);  // 12,800,000
    __half* h          = (__half*)(ws + 20401056);               // alias of cb16+p_out
    _Float16* Wt       = (_Float16*)(ws + 46001056);             // 65,536

    const int nb = (N_NODES + SCAN_EPB - 1) / SCAN_EPB;   // 98

    hist_kernel<<<2 * HR * HC, 256, 0, stream>>>(src, dst, rank, partial_in, partial_out);
    fused_reduce_kernel<<<nb, 256, 0, stream>>>(partial_in, partial_out, chunk_base16,
                                                deg_in, rs_out, spart, N_NODES);
    scan_part2<<<1, 128, 0, stream>>>(spart, sbases, nb);
    scan_part3<<<nb, SCAN_TPB, 0, stream>>>(deg_in, sbases, row_ptr, N_NODES);
    fill_kernel<<<(N_EDGES / 4 + 255) / 256, 256, 0, stream>>>(src, dst, ew, row_ptr,
                                                               chunk_base16, rank, ed, N_EDGES);
    wt_kernel<<<(IN_F * OUT_F + 255) / 256, 256, 0, stream>>>(weight, Wt);
    gemm_mfma_kernel<<<(N_NODES + GM_ROWS - 1) / GM_ROWS, 256, 0, stream>>>(feat, Wt, rs_out, h, N_NODES);
    gather_kernel<<<(N_NODES + 3) / 4, 256, 0, stream>>>(h, ed, row_ptr, out, N_NODES);
}

// Round 7
// 376.762 us; speedup vs baseline: 1.1052x; 1.0012x over previous
//
#include <hip/hip_runtime.h>
#include <hip/hip_fp16.h>
#include <math.h>

#define N_NODES 100000
#define N_EDGES 1600000
#define IN_F 256
#define OUT_F 128
#define SCAN_TPB 256
#define SCAN_EPB 1024

// hist partition: R node ranges x C edge chunks, packed 16-bit LDS bins
#define HR 4
#define HRANGE 25000          // nodes per range (50 KB LDS as packed u16)
#define HC 64
#define HCHUNK 25000          // edges per chunk (divisible by 4)
#define PWORDS (N_NODES / 2)  // packed words per chunk row (50,000)

// gemm tiling
#define GM_ROWS 64            // rows per block
#define BK 32                 // K-tile (one 16x16x32 MFMA k-step)

typedef _Float16 h8 __attribute__((ext_vector_type(8)));
typedef float f4 __attribute__((ext_vector_type(4)));
// clang ext-vector types for __builtin_nontemporal_* (HIP_vector_type structs are rejected)
typedef int   i4v __attribute__((ext_vector_type(4)));
typedef int   i2v __attribute__((ext_vector_type(2)));
typedef float f4v __attribute__((ext_vector_type(4)));

// async global->LDS, 16B per lane; dest is wave-uniform base + lane*16 (linear)
#define GLD16(gp, lp) __builtin_amdgcn_global_load_lds( \
    (const __attribute__((address_space(1))) unsigned int*)(gp), \
    (__attribute__((address_space(3))) unsigned int*)(lp), 16, 0, 0)

// ---------------- LDS-privatized histogram, packed 16-bit bins ----------------
// grid = HC x (2 type x HR) = 512 blocks. type 0: dst (+ per-edge rank),
// type 1: src. Counts per (chunk,node) < 25000 so 16-bit halves never overflow.
__global__ __launch_bounds__(256) void hist_kernel(
        const int* __restrict__ src, const int* __restrict__ dst,
        int* __restrict__ rank, unsigned int* __restrict__ partial_in,
        unsigned int* __restrict__ partial_out) {
    __shared__ unsigned int bins[HRANGE / 2];   // 50,000 B
    int b = blockIdx.x;
    int c = b >> 3;          // 0..63 chunk
    int tr = b & 7;
    int type = tr >> 2;      // 0 = dst, 1 = src
    int r = tr & 3;          // 0..3 range
    for (int i = threadIdx.x; i < HRANGE / 2; i += 256) bins[i] = 0;
    __syncthreads();
    const int* nodes = type ? src : dst;
    const int e0 = c * HCHUNK;
    const int lo = r * HRANGE;
    const int ngroups = HCHUNK / 4;   // 6250
    for (int g = threadIdx.x; g < ngroups; g += 256) {
        int e = e0 + g * 4;
        int4 n4 = *(const int4*)(nodes + e);
        int nn[4] = {n4.x, n4.y, n4.z, n4.w};
        #pragma unroll
        for (int j = 0; j < 4; ++j) {
            unsigned loc = (unsigned)(nn[j] - lo);
            if (loc < (unsigned)HRANGE) {
                unsigned sh = (loc & 1) * 16;
                unsigned old = atomicAdd(&bins[loc >> 1], 1u << sh);
                if (type == 0) rank[e + j] = (int)((old >> sh) & 0xffffu);
            }
        }
    }
    __syncthreads();
    unsigned int* part = type ? partial_out : partial_in;
    unsigned int* dstp = part + (size_t)c * PWORDS + (lo >> 1);
    for (int i = threadIdx.x; i < HRANGE / 2; i += 256) dstp[i] = bins[i];
}

// ---------------- fused reduce: deg_in + chunk_base16 + rs_out + scan partials ----------------
// block = 256 threads x 4 nodes = 1024 nodes (matches SCAN_EPB)
__global__ __launch_bounds__(256) void fused_reduce_kernel(
        const unsigned int* __restrict__ partial_in,
        const unsigned int* __restrict__ partial_out,
        unsigned short* __restrict__ chunk_base16,
        int* __restrict__ deg_in, float* __restrict__ rs_out,
        int* __restrict__ spart, int N) {
    __shared__ int tmp[256];
    int t = threadIdx.x;
    int n0 = blockIdx.x * SCAN_EPB + t * 4;
    int run[4] = {0, 0, 0, 0};
    int sout[4] = {0, 0, 0, 0};
    if (n0 < N) {
        const int w0 = n0 >> 1;    // word offset (n0 multiple of 4 -> even)
        #pragma unroll 4
        for (int c = 0; c < HC; ++c) {
            // chunk_base = running sum of per-chunk dst counts
            ushort4 cb;
            cb.x = (unsigned short)run[0]; cb.y = (unsigned short)run[1];
            cb.z = (unsigned short)run[2]; cb.w = (unsigned short)run[3];
            *(ushort4*)(chunk_base16 + (size_t)c * N_NODES + n0) = cb;
            uint2 pi = *(const uint2*)(partial_in + (size_t)c * PWORDS + w0);
            run[0] += (int)(pi.x & 0xffffu);  run[1] += (int)(pi.x >> 16);
            run[2] += (int)(pi.y & 0xffffu);  run[3] += (int)(pi.y >> 16);
            uint2 po = *(const uint2*)(partial_out + (size_t)c * PWORDS + w0);
            sout[0] += (int)(po.x & 0xffffu); sout[1] += (int)(po.x >> 16);
            sout[2] += (int)(po.y & 0xffffu); sout[3] += (int)(po.y >> 16);
        }
        *(int4*)(deg_in + n0) = make_int4(run[0], run[1], run[2], run[3]);
        float4 rs;
        rs.x = rsqrtf((float)(sout[0] < 1 ? 1 : sout[0]));
        rs.y = rsqrtf((float)(sout[1] < 1 ? 1 : sout[1]));
        rs.z = rsqrtf((float)(sout[2] < 1 ? 1 : sout[2]));
        rs.w = rsqrtf((float)(sout[3] < 1 ? 1 : sout[3]));
        *(float4*)(rs_out + n0) = rs;
    }
    tmp[t] = run[0] + run[1] + run[2] + run[3];
    __syncthreads();
    for (int off = 128; off > 0; off >>= 1) {
        if (t < off) tmp[t] += tmp[t + off];
        __syncthreads();
    }
    if (t == 0) spart[blockIdx.x] = tmp[0];
}

// ---------------- scan over block partials + final row_ptr ----------------
__global__ __launch_bounds__(128) void scan_part2(const int* __restrict__ partials,
                                                  int* __restrict__ bases, int nb) {
    __shared__ int tmp[128];
    int t = threadIdx.x;
    int v = (t < nb) ? partials[t] : 0;
    tmp[t] = v;
    __syncthreads();
    int x = v;
    for (int off = 1; off < 128; off <<= 1) {
        int y = (t >= off) ? tmp[t - off] : 0;
        __syncthreads();
        x += y;
        tmp[t] = x;
        __syncthreads();
    }
    if (t < nb) bases[t] = x - v;   // exclusive
}

__global__ __launch_bounds__(SCAN_TPB) void scan_part3(const int* __restrict__ deg,
                                                       const int* __restrict__ bases,
                                                       int* __restrict__ row_ptr, int N) {
    __shared__ int tmp[SCAN_TPB];
    int t = threadIdx.x;
    int i0 = blockIdx.x * SCAN_EPB + t * 4;
    int v[4];
    int s = 0;
    #pragma unroll
    for (int j = 0; j < 4; ++j) { v[j] = (i0 + j < N) ? deg[i0 + j] : 0; s += v[j]; }
    tmp[t] = s;
    __syncthreads();
    int x = s;
    for (int off = 1; off < SCAN_TPB; off <<= 1) {
        int y = (t >= off) ? tmp[t - off] : 0;
        __syncthreads();
        x += y;
        tmp[t] = x;
        __syncthreads();
    }
    int excl = bases[blockIdx.x] + x - s;
    #pragma unroll
    for (int j = 0; j < 4; ++j) {
        if (i0 + j < N) row_ptr[i0 + j] = excl;
        excl += v[j];
    }
    if (blockIdx.x == gridDim.x - 1 && t == SCAN_TPB - 1) row_ptr[N] = bases[blockIdx.x] + x;
}

// ---------------- atomic-free fill: dst-grouped packed (src, ew), int4 loads ----------------
// Edge-order streams (src/dst/ew/rank) are read once -> nontemporal, so the
// randomly-gathered chunk_base16 and row_ptr tables keep their L2 residency.
__global__ __launch_bounds__(256) void fill_kernel(
        const int* __restrict__ src, const int* __restrict__ dst,
        const float* __restrict__ ew, const int* __restrict__ row_ptr,
        const unsigned short* __restrict__ chunk_base16,
        const int* __restrict__ rank, int2* __restrict__ ed, int E) {
    int e0 = (blockIdx.x * 256 + threadIdx.x) * 4;
    if (e0 >= E) return;
    i4v s4 = __builtin_nontemporal_load((const i4v*)(src + e0));
    i4v d4 = __builtin_nontemporal_load((const i4v*)(dst + e0));
    f4v w4 = __builtin_nontemporal_load((const f4v*)(ew + e0));
    i4v r4 = __builtin_nontemporal_load((const i4v*)(rank + e0));
    int c = e0 / HCHUNK;   // groups never straddle chunks (HCHUNK % 4 == 0)
    const unsigned short* cb = chunk_base16 + (size_t)c * N_NODES;
    #pragma unroll
    for (int j = 0; j < 4; ++j) {
        int d = d4[j];
        int p = row_ptr[d] + (int)cb[d] + r4[j];
        unsigned long long v = (unsigned long long)(unsigned int)s4[j] |
                               ((unsigned long long)(unsigned int)__float_as_int(w4[j]) << 32);
        __builtin_nontemporal_store(v, (unsigned long long*)&ed[p]);
    }
}

// ---------------- Wt[n][k] = (f16) W[k][n] ----------------
__global__ void wt_kernel(const float* __restrict__ W, _Float16* __restrict__ Wt) {
    int i = blockIdx.x * blockDim.x + threadIdx.x;
    if (i < IN_F * OUT_F) {
        int n = i >> 8;
        int k = i & 255;
        Wt[i] = (_Float16)W[k * OUT_F + n];
    }
}

__device__ __forceinline__ float fast_tanh(float x) {
    // tanh(x) = 1 - 2/(e^2x + 1); exact at +/-inf, error << f16 quantization
    float e = __expf(2.0f * x);
    return 1.0f - 2.0f / (e + 1.0f);
}

// ---------------- h = tanh(rs[row] * (feat @ W)), f16 MFMA ----------------
// 2-phase async pipeline (T3 minimum recipe): per K-tile (BK=32) both A
// (64x32 f32, 8 KB) and B (128x32 f16, 8 KB) are staged into double-buffered
// LDS via global_load_lds width=16 (4 calls/wave), issued BEFORE computing
// the current tile; one __syncthreads() (vmcnt+lgkm drain) per tile. The
// intrinsic has no dest VGPR, so the compiler cannot sink the loads back to
// the use point (which defeated rounds 0-3; VGPR_Count 88 was the tell).
// A's LDS rows (128 B stride) would be 32-way bank-conflicted, so the 16B
// granule index is XOR-swizzled with (row&7) on the GLOBAL SOURCE address
// (gload_lds writes linearly) and the same XOR is applied on read-back.
// B's 64 B row stride is naturally bank-balanced. LDS total 32 KB -> 4
// blocks/CU (16 waves/CU). rs commutes through the matmul and is applied
// on the f32 accumulator in the epilogue.
__global__ __launch_bounds__(256, 4) void gemm_mfma_kernel(
        const float* __restrict__ feat, const _Float16* __restrict__ Wt,
        const float* __restrict__ rs_out, __half* __restrict__ h, int N) {
    __shared__ float    a_lds[2][GM_ROWS * BK];   // 2 x 8,192 B
    __shared__ _Float16 b_lds[2][OUT_F * BK];     // 2 x 8,192 B

    const int tid  = threadIdx.x;
    const int wave = tid >> 6;
    const int lane = tid & 63;
    const int m    = lane & 15;
    const int quad = lane >> 4;
    const int n0   = wave * 32;
    const int r0   = blockIdx.x * GM_ROWS;

    // ---- staging address setup (wave w: A-calls {2w,2w+1}, B-calls {2w,2w+1})
    // A call i covers LDS rows 8i..8i+7; lane l -> row 8i+(l>>3), LDS granule
    // l&7 (linear), source granule (l&7)^((l>>3)&7)  [row&7 == (l>>3)&7]
    const int l3 = lane >> 3;
    const int ag = (lane & 7) ^ l3;
    int arow0 = r0 + 16 * wave + l3;      if (arow0 >= N) arow0 = N - 1;
    int arow1 = r0 + 16 * wave + 8 + l3;  if (arow1 >= N) arow1 = N - 1;
    const float* ga0 = feat + (size_t)arow0 * IN_F + ag * 4;
    const float* ga1 = feat + (size_t)arow1 * IN_F + ag * 4;
    // B call i covers LDS rows 16i..16i+15; lane l -> row 16i+(l>>2), granule l&3
    const int brow0 = 32 * wave + (lane >> 2);
    const int brow1 = 32 * wave + 16 + (lane >> 2);
    const _Float16* gb0 = Wt + (size_t)brow0 * IN_F + (lane & 3) * 8;
    const _Float16* gb1 = Wt + (size_t)brow1 * IN_F + (lane & 3) * 8;

    f4 acc[4][2];
    #pragma unroll
    for (int t = 0; t < 4; ++t) {
        acc[t][0] = (f4){0.f, 0.f, 0.f, 0.f};
        acc[t][1] = (f4){0.f, 0.f, 0.f, 0.f};
    }

    // prologue: stage k-tile 0 into buf 0
    GLD16(ga0, &a_lds[0][(16 * wave) * BK]);
    GLD16(ga1, &a_lds[0][(16 * wave + 8) * BK]);
    GLD16(gb0, &b_lds[0][(32 * wave) * BK]);
    GLD16(gb1, &b_lds[0][(32 * wave + 16) * BK]);
    __syncthreads();

    #pragma unroll
    for (int kt = 0; kt < IN_F / BK; ++kt) {      // 8 k-tiles
        const int cb = kt & 1;
        if (kt < IN_F / BK - 1) {                 // stage next tile (async)
            const int nb2 = cb ^ 1;
            const int ko = (kt + 1) * BK;
            GLD16(ga0 + ko, &a_lds[nb2][(16 * wave) * BK]);
            GLD16(ga1 + ko, &a_lds[nb2][(16 * wave + 8) * BK]);
            GLD16(gb0 + ko, &b_lds[nb2][(32 * wave) * BK]);
            GLD16(gb1 + ko, &b_lds[nb2][(32 * wave + 16) * BK]);
            __builtin_amdgcn_sched_barrier(0);    // keep stages issued first
        }
        // B fragments: this wave's two 16-col tiles
        h8 b0 = *(const h8*)&b_lds[cb][(n0 + m) * BK + quad * 8];
        h8 b1 = *(const h8*)&b_lds[cb][(n0 + 16 + m) * BK + quad * 8];
        #pragma unroll
        for (int t = 0; t < 4; ++t) {
            const int ar = t * 16 + m;            // row in buffer; ar&7 == m&7
            float4 alo = *(const float4*)&a_lds[cb][ar * BK + (((quad * 2)     ^ (m & 7)) * 4)];
            float4 ahi = *(const float4*)&a_lds[cb][ar * BK + (((quad * 2 + 1) ^ (m & 7)) * 4)];
            h8 a;
            a[0] = (_Float16)alo.x; a[1] = (_Float16)alo.y;
            a[2] = (_Float16)alo.z; a[3] = (_Float16)alo.w;
            a[4] = (_Float16)ahi.x; a[5] = (_Float16)ahi.y;
            a[6] = (_Float16)ahi.z; a[7] = (_Float16)ahi.w;
            acc[t][0] = __builtin_amdgcn_mfma_f32_16x16x32_f16(a, b0, acc[t][0], 0, 0, 0);
            acc[t][1] = __builtin_amdgcn_mfma_f32_16x16x32_f16(a, b1, acc[t][1], 0, 0, 0);
        }
        __syncthreads();   // drains vmcnt(0): staged tile ready; all waves done with cb
    }

    #pragma unroll
    for (int t = 0; t < 4; ++t) {
        const int crow = r0 + t * 16 + quad * 4;
        float4 rs4 = *(const float4*)&rs_out[crow];   // rows contiguous, 16B-aligned
        const float rsv[4] = {rs4.x, rs4.y, rs4.z, rs4.w};
        #pragma unroll
        for (int r = 0; r < 4; ++r) {
            const int rr = crow + r;
            if (rr < N) {
                h[(size_t)rr * OUT_F + n0 + m]      = __float2half(fast_tanh(acc[t][0][r] * rsv[r]));
                h[(size_t)rr * OUT_F + n0 + 16 + m] = __float2half(fast_tanh(acc[t][1][r] * rsv[r]));
            }
        }
    }
}

// ---------------- gather: one wave per dst node, 4 edge-slots x 4-deep unroll ----------------
// ed is a read-once stream and out a write-once stream: both nontemporal so
// L2 retention is spent on the randomly re-read h rows (~16 reuses/row).
// Per iteration: batch the 4 independent ed loads first, then the 4 dependent
// h-row loads, so the wave presents two clean memory waves instead of four
// serial ed->h pairs.
__global__ __launch_bounds__(256) void gather_kernel(
        const __half* __restrict__ h, const int2* __restrict__ ed,
        const int* __restrict__ row_ptr, float* __restrict__ out, int N) {
    int wave = threadIdx.x >> 6;
    int lane = threadIdx.x & 63;
    int node = blockIdx.x * 4 + wave;
    if (node >= N) return;
    int lo = row_ptr[node];
    int hi = row_ptr[node + 1];
    int p = lane >> 4;       // edge slot 0..3
    int c = lane & 15;       // feature octet: feats 8c..8c+7
    float acc[4][8];
    #pragma unroll
    for (int g = 0; g < 4; ++g)
        #pragma unroll
        for (int i = 0; i < 8; ++i) acc[g][i] = 0.f;

    for (int j = lo; j < hi; j += 16) {
        i2v e[4];
        #pragma unroll
        for (int g = 0; g < 4; ++g) {
            int jj = j + g * 4 + p;
            e[g] = (jj < hi) ? __builtin_nontemporal_load((const i2v*)&ed[jj]) : (i2v){0, 0};
        }
        #pragma unroll
        for (int g = 0; g < 4; ++g) {
            float w = __int_as_float(e[g][1]);
            int4 rrow = *(const int4*)(h + (size_t)e[g][0] * OUT_F + c * 8);
            float2 t;
            t = __half22float2(*(__half2*)&rrow.x); acc[g][0] += w * t.x; acc[g][1] += w * t.y;
            t = __half22float2(*(__half2*)&rrow.y); acc[g][2] += w * t.x; acc[g][3] += w * t.y;
            t = __half22float2(*(__half2*)&rrow.z); acc[g][4] += w * t.x; acc[g][5] += w * t.y;
            t = __half22float2(*(__half2*)&rrow.w); acc[g][6] += w * t.x; acc[g][7] += w * t.y;
        }
    }
    float v[8];
    #pragma unroll
    for (int i = 0; i < 8; ++i) {
        v[i] = (acc[0][i] + acc[1][i]) + (acc[2][i] + acc[3][i]);
        v[i] += __shfl_xor(v[i], 16);
        v[i] += __shfl_xor(v[i], 32);
    }
    if (p == 0) {
        int deg = hi - lo; if (deg < 1) deg = 1;
        float rs = rsqrtf((float)deg);
        float* op = out + (size_t)node * OUT_F + c * 8;
        f4v o0 = {v[0] * rs, v[1] * rs, v[2] * rs, v[3] * rs};
        f4v o1 = {v[4] * rs, v[5] * rs, v[6] * rs, v[7] * rs};
        __builtin_nontemporal_store(o0, (f4v*)op);
        __builtin_nontemporal_store(o1, (f4v*)(op + 4));
    }
}

extern "C" void kernel_launch(void* const* d_in, const int* in_sizes, int n_in,
                              void* d_out, int out_size, void* d_ws, size_t ws_size,
                              hipStream_t stream) {
    const float* feat   = (const float*)d_in[0];
    const float* weight = (const float*)d_in[1];
    const float* ew     = (const float*)d_in[2];
    const int*   src    = (const int*)d_in[3];
    const int*   dst    = (const int*)d_in[4];
    float* out = (float*)d_out;

    // workspace layout with aliasing (total 46.07 MB):
    //   ed (12.8M)  overlays partial_in  (dead after fused_reduce)
    //   h  (25.6M)  overlays chunk_base16 + partial_out (dead after fill/reduce)
    char* ws = (char*)d_ws;
    float* rs_out      = (float*)(ws);                       // 400,000
    int*   deg_in      = (int*)(ws + 400000);                // 400,000
    int*   row_ptr     = (int*)(ws + 800000);                // 400,016
    int*   spart       = (int*)(ws + 1200016);               // 512
    int*   sbases      = (int*)(ws + 1200528);               // 512
    int*   rank        = (int*)(ws + 1201056);               // 6,400,000
    unsigned int* partial_in  = (unsigned int*)(ws + 7601056);   // 12,800,000
    int2*  ed          = (int2*)(ws + 7601056);                  // alias ^
    unsigned short* chunk_base16 = (unsigned short*)(ws + 20401056); // 12,800,000
    unsigned int* partial_out = (unsigned int*)(ws + 33201056);  // 12,800,000
    __half* h          = (__half*)(ws + 20401056);               // alias of cb16+p_out
    _Float16* Wt       = (_Float16*)(ws + 46001056);             // 65,536

    const int nb = (N_NODES + SCAN_EPB - 1) / SCAN_EPB;   // 98

    hist_kernel<<<2 * HR * HC, 256, 0, stream>>>(src, dst, rank, partial_in, partial_out);
    fused_reduce_kernel<<<nb, 256, 0, stream>>>(partial_in, partial_out, chunk_base16,
                                                deg_in, rs_out, spart, N_NODES);
    scan_part2<<<1, 128, 0, stream>>>(spart, sbases, nb);
    scan_part3<<<nb, SCAN_TPB, 0, stream>>>(deg_in, sbases, row_ptr, N_NODES);
    fill_kernel<<<(N_EDGES / 4 + 255) / 256, 256, 0, stream>>>(src, dst, ew, row_ptr,
                                                               chunk_base16, rank, ed, N_EDGES);
    wt_kernel<<<(IN_F * OUT_F + 255) / 256, 256, 0, stream>>>(weight, Wt);
    gemm_mfma_kernel<<<(N_NODES + GM_ROWS - 1) / GM_ROWS, 256, 0, stream>>>(feat, Wt, rs_out, h, N_NODES);
    gather_kernel<<<(N_NODES + 3) / 4, 256, 0, stream>>>(h, ed, row_ptr, out, N_NODES);
}